// Round 13
// baseline (128.861 us; speedup 1.0000x reference)
//
#include <hip/hip_runtime.h>

// Event-to-image: B=16, N=500000 events (t,x,y,p) f32 -> (16,720,1280,3) f32.
// Last-event-wins per pixel: p==1 -> (0,255,255); p==0 -> (255,0,255);
// untouched -> (255,255,510). Order-independent via max over
// key = ((event_idx+1)<<1)|p (20 bits), pk = pos<<20 | key,
// pos = (y&1)*1280 + x (12 bits) -- 2-row bands.
//
// R13 = R12 (81.9us) + two micro-opts:
// (1) scatter full-block specialization: unguarded loads in batches of 4
//     (16 VGPRs in flight), histogram atomics deferred per batch -> MLP.
// (2) render per-4-pixel conversion: one uint4 LDS read + 12 selects +
//     3 contiguous nt float4 stores; kills the div/mod-by-3 per float and
//     24 scalar LDS reads per 2 outputs.

#define WIDTH   1280
#define HEIGHT  720
#define BATCH   16
#define NEV     500000
#define THREADS 512                         // scatter block
#define EPT     16
#define EVPB    (THREADS * EPT)             // 8192 events per block
#define BPB     ((NEV + EVPB - 1) / EVPB)   // 62 blocks per batch
#define NBLK    (BATCH * BPB)               // 992
#define NBANDS  360                         // 2-row bands per batch
#define PH      (NBANDS + 1)                // 361 prefix entries per block
#define RTHREADS 256                        // render block

typedef float f4 __attribute__((ext_vector_type(4)));

// ws layout: [0, NBLK*PH*4)=pref_g (1.43 MB); [0x400000, +NBLK*EVPB*4)=bins (32.5 MB)

__global__ __launch_bounds__(THREADS, 8) void scatter_k(const float4* __restrict__ ev,
                                                        unsigned int* __restrict__ pref_g,
                                                        unsigned int* __restrict__ bins) {
    __shared__ unsigned int hist[NBANDS];
    __shared__ unsigned int offs[NBANDS];
    __shared__ unsigned int wtot[8];
    __shared__ unsigned int stage[EVPB];     // 32 KB (total ~34.9 KB -> 4 blocks/CU)

    int t = threadIdx.x;
    int batch = blockIdx.x / BPB;
    int blk   = blockIdx.x % BPB;
    int ev0   = blk * EVPB;
    int cnt   = NEV - ev0; if (cnt > EVPB) cnt = EVPB;
    const f4* bevv = (const f4*)(ev + (size_t)batch * NEV + ev0);

    if (t < NBANDS) hist[t] = 0u;
    __syncthreads();

    // pass 1: ONE global read (nt), pack to registers, histogram
    unsigned int pkd[EPT];                   // y<<12 | x<<1 | p ; 0xFFFFFFFF = tail
    if (cnt == EVPB) {
        // full block (61/62): unguarded, batches of 4 loads then 4 atomics
#pragma unroll
        for (int h = 0; h < EPT / 4; ++h) {
            f4 vv[4];
#pragma unroll
            for (int k = 0; k < 4; ++k)
                vv[k] = __builtin_nontemporal_load(&bevv[t + (h * 4 + k) * THREADS]);
#pragma unroll
            for (int k = 0; k < 4; ++k) {
                unsigned int yi = (unsigned int)(int)vv[k].z;
                unsigned int xi = (unsigned int)(int)vv[k].y;
                unsigned int pb = (vv[k].w == 1.0f) ? 1u : 0u;
                pkd[h * 4 + k] = (yi << 12) | (xi << 1) | pb;
                atomicAdd(&hist[yi >> 1], 1u);
            }
        }
    } else {
#pragma unroll
        for (int k = 0; k < EPT; ++k) {
            int e = t + k * THREADS;
            unsigned int c = 0xFFFFFFFFu;
            if (e < cnt) {
                f4 v = __builtin_nontemporal_load(&bevv[e]);
                unsigned int yi = (unsigned int)(int)v.z;
                unsigned int xi = (unsigned int)(int)v.y;
                unsigned int pb = (v.w == 1.0f) ? 1u : 0u;
                c = (yi << 12) | (xi << 1) | pb;
                atomicAdd(&hist[yi >> 1], 1u);
            }
            pkd[k] = c;
        }
    }
    __syncthreads();

    // exclusive prefix over 360 bands: threads 0..89 own 4 bands; shfl scan
    unsigned int own = 0u;
    int b4 = t * 4;
    if (t < 90) own = hist[b4] + hist[b4 + 1] + hist[b4 + 2] + hist[b4 + 3];
    unsigned int incl = own;
    for (int d = 1; d < 64; d <<= 1) {
        unsigned int n = __shfl_up(incl, d);
        if ((t & 63) >= d) incl += n;
    }
    if ((t & 63) == 63) wtot[t >> 6] = incl;   // waves 2..7 contribute 0
    __syncthreads();
    unsigned int wbase = 0u;
    for (int w = 0; w < (t >> 6); ++w) wbase += wtot[w];
    unsigned int total = 0u;
    for (int w = 0; w < 8; ++w) total += wtot[w];        // == cnt
    if (t < 90) {
        unsigned int run = wbase + incl - own;
        offs[b4] = run;          run += hist[b4];
        offs[b4 + 1] = run;      run += hist[b4 + 1];
        offs[b4 + 2] = run;      run += hist[b4 + 2];
        offs[b4 + 3] = run;
    }
    __syncthreads();

    // publish per-block band prefix BEFORE pass 2 mutates offs
    unsigned int* pg = pref_g + (size_t)blockIdx.x * PH;
    if (t < PH) pg[t] = (t < NBANDS) ? offs[t] : total;
    __syncthreads();

    // pass 2: from REGISTERS, rank, place sorted in stage
    if (cnt == EVPB) {
#pragma unroll
        for (int k = 0; k < EPT; ++k) {
            unsigned int c   = pkd[k];
            unsigned int yi  = c >> 12;
            unsigned int xi  = (c >> 1) & 0x7FFu;
            unsigned int pos = (yi & 1u) * 1280u + xi;
            unsigned int e   = (unsigned int)(t + k * THREADS);
            unsigned int pk  = (pos << 20)
                             | (((unsigned int)ev0 + e + 1u) << 1) | (c & 1u);
            unsigned int slot = atomicAdd(&offs[yi >> 1], 1u);
            stage[slot] = pk;
        }
    } else {
#pragma unroll
        for (int k = 0; k < EPT; ++k) {
            unsigned int c = pkd[k];
            if (c != 0xFFFFFFFFu) {
                unsigned int yi  = c >> 12;
                unsigned int xi  = (c >> 1) & 0x7FFu;
                unsigned int pos = (yi & 1u) * 1280u + xi;
                unsigned int e   = (unsigned int)(t + k * THREADS);
                unsigned int pk  = (pos << 20)
                                 | (((unsigned int)ev0 + e + 1u) << 1) | (c & 1u);
                unsigned int slot = atomicAdd(&offs[yi >> 1], 1u);
                stage[slot] = pk;
            }
        }
    }
    __syncthreads();

    // write the sorted chunk, fully coalesced (keep in L2/L3 for render)
    uint4* dst = (uint4*)(bins + (size_t)blockIdx.x * EVPB);
    const uint4* src = (const uint4*)stage;
    for (int k = t; k < EVPB / 4; k += THREADS)
        dst[k] = src[k];
}

__global__ __launch_bounds__(RTHREADS) void render_k(const unsigned int* __restrict__ pref_g,
                                                     const unsigned int* __restrict__ bins,
                                                     float4* __restrict__ out) {
    __shared__ __align__(16) unsigned int win[2 * WIDTH];  // 2560 px, 10 KB
    __shared__ unsigned int segbase[BPB];
    __shared__ unsigned int segpref[65];

    int t = threadIdx.x;
    int bandid = blockIdx.x;                 // batch*360 + band
    int batch = bandid / NBANDS;
    int band  = bandid - batch * NBANDS;

    for (int x = t; x < 2 * WIDTH; x += RTHREADS) win[x] = 0u;

    unsigned int mycnt = 0u;
    if (t < BPB) {
        const unsigned int* pg = pref_g + (size_t)(batch * BPB + t) * PH + band;
        unsigned int p0 = pg[0], p1 = pg[1];
        segbase[t] = (unsigned int)((batch * BPB + t) * EVPB) + p0;
        mycnt = p1 - p0;
    }
    if (t < 64) {                            // wave-0 inclusive scan of 62 counts
        unsigned int v = mycnt;
        for (int d = 1; d < 64; d <<= 1) {
            unsigned int n = __shfl_up(v, d);
            if (t >= d) v += n;
        }
        if (t == 0) segpref[0] = 0u;
        segpref[t + 1] = v;
    }
    __syncthreads();

    unsigned int total = segpref[BPB];       // ~1389
    for (unsigned int j = t; j < total; j += RTHREADS) {
        int lo = 0, hi = BPB - 1;            // largest s with segpref[s] <= j
        while (lo < hi) {
            int mid = (lo + hi + 1) >> 1;
            if (segpref[mid] <= j) lo = mid; else hi = mid - 1;
        }
        unsigned int pk = bins[segbase[lo] + (j - segpref[lo])];
        atomicMax(&win[pk >> 20], pk & 0xFFFFFu);   // LDS atomic
    }
    __syncthreads();

    // write two image rows, 4 pixels per unit: uint4 LDS read -> 12 floats
    // -> 3 contiguous nt float4 stores. 640 units per band.
    f4* orow = (f4*)out + (size_t)bandid * (2 * WIDTH * 3 / 4);
    const uint4* w4 = (const uint4*)win;
    for (int g = t; g < 2 * WIDTH / 4; g += RTHREADS) {
        uint4 ww = w4[g];
        unsigned int ks[4] = { ww.x, ww.y, ww.z, ww.w };
        float v12[12];
#pragma unroll
        for (int q = 0; q < 4; ++q) {
            unsigned int k = ks[q];
            float y0, y1, y2;
            if (k == 0u) { y0 = 255.0f; y1 = 255.0f; y2 = 510.0f; }
            else {
                y0 = (k & 1u) ? 0.0f : 255.0f;
                y1 = (k & 1u) ? 255.0f : 0.0f;
                y2 = 255.0f;
            }
            v12[3 * q + 0] = y0;
            v12[3 * q + 1] = y1;
            v12[3 * q + 2] = y2;
        }
        f4 o0 = { v12[0], v12[1], v12[2],  v12[3] };
        f4 o1 = { v12[4], v12[5], v12[6],  v12[7] };
        f4 o2 = { v12[8], v12[9], v12[10], v12[11] };
        __builtin_nontemporal_store(o0, orow + 3 * g + 0);
        __builtin_nontemporal_store(o1, orow + 3 * g + 1);
        __builtin_nontemporal_store(o2, orow + 3 * g + 2);
    }
}

extern "C" void kernel_launch(void* const* d_in, const int* in_sizes, int n_in,
                              void* d_out, int out_size, void* d_ws, size_t ws_size,
                              hipStream_t stream) {
    const float4* ev = (const float4*)d_in[0];
    unsigned int* pref_g = (unsigned int*)d_ws;
    unsigned int* bins   = (unsigned int*)((char*)d_ws + 0x400000);
    float4* out = (float4*)d_out;

    scatter_k<<<NBLK, THREADS, 0, stream>>>(ev, pref_g, bins);
    render_k<<<BATCH * NBANDS, RTHREADS, 0, stream>>>(pref_g, bins, out);
}

// Round 14
// 80.792 us; speedup vs baseline: 1.5950x; 1.5950x over previous
//
#include <hip/hip_runtime.h>

// Event-to-image: B=16, N=500000 events (t,x,y,p) f32 -> (16,720,1280,3) f32.
// Last-event-wins per pixel: p==1 -> (0,255,255); p==0 -> (255,0,255);
// untouched -> (255,255,510). Order-independent via max over
// key = ((event_idx+1)<<1)|p (20 bits), pk = pos<<20 | key,
// pos = (y&1)*1280 + x (12 bits) -- 2-row bands.
//
// R14 = R13 scatter (batched unguarded loads -> ~29us, proven by R13's
// per-kernel counters) + R12 render (per-thread single float4, interleaved
// nt stores). R13's render regression isolated: 3 consecutive float4 stores
// per thread = 48B-strided lanes per store instruction -> partial-line nt
// writes, WRITE_SIZE 278MB (1.57x), 3.3TB/s. Coalescing is per-instruction
// across lanes; revert to the proven write shape.

#define WIDTH   1280
#define HEIGHT  720
#define BATCH   16
#define NEV     500000
#define THREADS 512                         // scatter block
#define EPT     16
#define EVPB    (THREADS * EPT)             // 8192 events per block
#define BPB     ((NEV + EVPB - 1) / EVPB)   // 62 blocks per batch
#define NBLK    (BATCH * BPB)               // 992
#define NBANDS  360                         // 2-row bands per batch
#define PH      (NBANDS + 1)                // 361 prefix entries per block
#define RTHREADS 256                        // render block

typedef float f4 __attribute__((ext_vector_type(4)));

// ws layout: [0, NBLK*PH*4)=pref_g (1.43 MB); [0x400000, +NBLK*EVPB*4)=bins (32.5 MB)

__global__ __launch_bounds__(THREADS, 8) void scatter_k(const float4* __restrict__ ev,
                                                        unsigned int* __restrict__ pref_g,
                                                        unsigned int* __restrict__ bins) {
    __shared__ unsigned int hist[NBANDS];
    __shared__ unsigned int offs[NBANDS];
    __shared__ unsigned int wtot[8];
    __shared__ unsigned int stage[EVPB];     // 32 KB (total ~34.9 KB -> 4 blocks/CU)

    int t = threadIdx.x;
    int batch = blockIdx.x / BPB;
    int blk   = blockIdx.x % BPB;
    int ev0   = blk * EVPB;
    int cnt   = NEV - ev0; if (cnt > EVPB) cnt = EVPB;
    const f4* bevv = (const f4*)(ev + (size_t)batch * NEV + ev0);

    if (t < NBANDS) hist[t] = 0u;
    __syncthreads();

    // pass 1: ONE global read (nt), pack to registers, histogram
    unsigned int pkd[EPT];                   // y<<12 | x<<1 | p ; 0xFFFFFFFF = tail
    if (cnt == EVPB) {
        // full block (61/62): unguarded, batches of 4 loads then 4 atomics
#pragma unroll
        for (int h = 0; h < EPT / 4; ++h) {
            f4 vv[4];
#pragma unroll
            for (int k = 0; k < 4; ++k)
                vv[k] = __builtin_nontemporal_load(&bevv[t + (h * 4 + k) * THREADS]);
#pragma unroll
            for (int k = 0; k < 4; ++k) {
                unsigned int yi = (unsigned int)(int)vv[k].z;
                unsigned int xi = (unsigned int)(int)vv[k].y;
                unsigned int pb = (vv[k].w == 1.0f) ? 1u : 0u;
                pkd[h * 4 + k] = (yi << 12) | (xi << 1) | pb;
                atomicAdd(&hist[yi >> 1], 1u);
            }
        }
    } else {
#pragma unroll
        for (int k = 0; k < EPT; ++k) {
            int e = t + k * THREADS;
            unsigned int c = 0xFFFFFFFFu;
            if (e < cnt) {
                f4 v = __builtin_nontemporal_load(&bevv[e]);
                unsigned int yi = (unsigned int)(int)v.z;
                unsigned int xi = (unsigned int)(int)v.y;
                unsigned int pb = (v.w == 1.0f) ? 1u : 0u;
                c = (yi << 12) | (xi << 1) | pb;
                atomicAdd(&hist[yi >> 1], 1u);
            }
            pkd[k] = c;
        }
    }
    __syncthreads();

    // exclusive prefix over 360 bands: threads 0..89 own 4 bands; shfl scan
    unsigned int own = 0u;
    int b4 = t * 4;
    if (t < 90) own = hist[b4] + hist[b4 + 1] + hist[b4 + 2] + hist[b4 + 3];
    unsigned int incl = own;
    for (int d = 1; d < 64; d <<= 1) {
        unsigned int n = __shfl_up(incl, d);
        if ((t & 63) >= d) incl += n;
    }
    if ((t & 63) == 63) wtot[t >> 6] = incl;   // waves 2..7 contribute 0
    __syncthreads();
    unsigned int wbase = 0u;
    for (int w = 0; w < (t >> 6); ++w) wbase += wtot[w];
    unsigned int total = 0u;
    for (int w = 0; w < 8; ++w) total += wtot[w];        // == cnt
    if (t < 90) {
        unsigned int run = wbase + incl - own;
        offs[b4] = run;          run += hist[b4];
        offs[b4 + 1] = run;      run += hist[b4 + 1];
        offs[b4 + 2] = run;      run += hist[b4 + 2];
        offs[b4 + 3] = run;
    }
    __syncthreads();

    // publish per-block band prefix BEFORE pass 2 mutates offs
    unsigned int* pg = pref_g + (size_t)blockIdx.x * PH;
    if (t < PH) pg[t] = (t < NBANDS) ? offs[t] : total;
    __syncthreads();

    // pass 2: from REGISTERS, rank, place sorted in stage
    if (cnt == EVPB) {
#pragma unroll
        for (int k = 0; k < EPT; ++k) {
            unsigned int c   = pkd[k];
            unsigned int yi  = c >> 12;
            unsigned int xi  = (c >> 1) & 0x7FFu;
            unsigned int pos = (yi & 1u) * 1280u + xi;
            unsigned int e   = (unsigned int)(t + k * THREADS);
            unsigned int pk  = (pos << 20)
                             | (((unsigned int)ev0 + e + 1u) << 1) | (c & 1u);
            unsigned int slot = atomicAdd(&offs[yi >> 1], 1u);
            stage[slot] = pk;
        }
    } else {
#pragma unroll
        for (int k = 0; k < EPT; ++k) {
            unsigned int c = pkd[k];
            if (c != 0xFFFFFFFFu) {
                unsigned int yi  = c >> 12;
                unsigned int xi  = (c >> 1) & 0x7FFu;
                unsigned int pos = (yi & 1u) * 1280u + xi;
                unsigned int e   = (unsigned int)(t + k * THREADS);
                unsigned int pk  = (pos << 20)
                                 | (((unsigned int)ev0 + e + 1u) << 1) | (c & 1u);
                unsigned int slot = atomicAdd(&offs[yi >> 1], 1u);
                stage[slot] = pk;
            }
        }
    }
    __syncthreads();

    // write the sorted chunk, fully coalesced (keep in L2/L3 for render)
    uint4* dst = (uint4*)(bins + (size_t)blockIdx.x * EVPB);
    const uint4* src = (const uint4*)stage;
    for (int k = t; k < EVPB / 4; k += THREADS)
        dst[k] = src[k];
}

__global__ __launch_bounds__(RTHREADS) void render_k(const unsigned int* __restrict__ pref_g,
                                                     const unsigned int* __restrict__ bins,
                                                     float4* __restrict__ out) {
    __shared__ unsigned int win[2 * WIDTH];  // 2560 px, 10 KB
    __shared__ unsigned int segbase[BPB];
    __shared__ unsigned int segpref[65];

    int t = threadIdx.x;
    int bandid = blockIdx.x;                 // batch*360 + band
    int batch = bandid / NBANDS;
    int band  = bandid - batch * NBANDS;

    for (int x = t; x < 2 * WIDTH; x += RTHREADS) win[x] = 0u;

    unsigned int mycnt = 0u;
    if (t < BPB) {
        const unsigned int* pg = pref_g + (size_t)(batch * BPB + t) * PH + band;
        unsigned int p0 = pg[0], p1 = pg[1];
        segbase[t] = (unsigned int)((batch * BPB + t) * EVPB) + p0;
        mycnt = p1 - p0;
    }
    if (t < 64) {                            // wave-0 inclusive scan of 62 counts
        unsigned int v = mycnt;
        for (int d = 1; d < 64; d <<= 1) {
            unsigned int n = __shfl_up(v, d);
            if (t >= d) v += n;
        }
        if (t == 0) segpref[0] = 0u;
        segpref[t + 1] = v;
    }
    __syncthreads();

    unsigned int total = segpref[BPB];       // ~1389
    for (unsigned int j = t; j < total; j += RTHREADS) {
        int lo = 0, hi = BPB - 1;            // largest s with segpref[s] <= j
        while (lo < hi) {
            int mid = (lo + hi + 1) >> 1;
            if (segpref[mid] <= j) lo = mid; else hi = mid - 1;
        }
        unsigned int pk = bins[segbase[lo] + (j - segpref[lo])];
        atomicMax(&win[pk >> 20], pk & 0xFFFFFu);   // LDS atomic
    }
    __syncthreads();

    // write two image rows: 2560 px * 3 ch = 1920 float4; one float4 per
    // thread per iteration -> lane-contiguous 1024B per store instruction
    f4* orow = (f4*)out + (size_t)bandid * (2 * WIDTH * 3 / 4);
    for (int j = t; j < 2 * WIDTH * 3 / 4; j += RTHREADS) {
        float vals[4];
#pragma unroll
        for (int c = 0; c < 4; ++c) {
            int fi = j * 4 + c;
            int px = fi / 3;
            int ch = fi - px * 3;
            unsigned int k = win[px];
            float val;
            if (k == 0u) val = (ch == 2) ? 510.0f : 255.0f;
            else if (ch == 2) val = 255.0f;
            else if (ch == 0) val = (k & 1u) ? 0.0f : 255.0f;
            else              val = (k & 1u) ? 255.0f : 0.0f;
            vals[c] = val;
        }
        f4 o = { vals[0], vals[1], vals[2], vals[3] };
        __builtin_nontemporal_store(o, orow + j);
    }
}

extern "C" void kernel_launch(void* const* d_in, const int* in_sizes, int n_in,
                              void* d_out, int out_size, void* d_ws, size_t ws_size,
                              hipStream_t stream) {
    const float4* ev = (const float4*)d_in[0];
    unsigned int* pref_g = (unsigned int*)d_ws;
    unsigned int* bins   = (unsigned int*)((char*)d_ws + 0x400000);
    float4* out = (float4*)d_out;

    scatter_k<<<NBLK, THREADS, 0, stream>>>(ev, pref_g, bins);
    render_k<<<BATCH * NBANDS, RTHREADS, 0, stream>>>(pref_g, bins, out);
}